// Round 15
// baseline (459.821 us; speedup 1.0000x reference)
//
#include <hip/hip_runtime.h>
#include <hip/hip_bf16.h>

// Problem constants (from setup_inputs: x = [2, 1024, 64] fp32)
constexpr int BB = 2;
constexpr int N  = 1024;
constexpr int C  = 64;
constexpr int S  = N * N;          // 1048576 = 2^20
constexpr int KSEL = S / 6;        // 174762 entries set to 1 per batch
constexpr int SEGSZ = 2048;        // compaction segment (line-aligned in out)
constexpr int NSEG  = S / SEGSZ;   // 512 segments per batch
constexpr int PBBLK = 64;          // pass-B grid (32 blocks per batch)

typedef double d4 __attribute__((ext_vector_type(4)));

// Order-preserving uint64 mapping of fp64 (monotone: a<b <=> key(a)<key(b))
__device__ __forceinline__ unsigned long long d2key(double d) {
    unsigned long long u = (unsigned long long)__double_as_longlong(d);
    return (u & 0x8000000000000000ULL) ? ~u : (u | 0x8000000000000000ULL);
}

__device__ __forceinline__ unsigned int aload(const unsigned int* p) {
    return __hip_atomic_load(p, __ATOMIC_RELAXED, __HIP_MEMORY_SCOPE_AGENT);
}
__device__ __forceinline__ void astore(unsigned int* p, unsigned int v) {
    (void)__hip_atomic_exchange(p, v, __ATOMIC_RELAXED, __HIP_MEMORY_SCOPE_AGENT);
}
__device__ __forceinline__ unsigned long long aload64(const unsigned long long* p) {
    return __hip_atomic_load(p, __ATOMIC_RELAXED, __HIP_MEMORY_SCOPE_AGENT);
}
__device__ __forceinline__ void astore64(unsigned long long* p, unsigned long long v) {
    (void)__hip_atomic_exchange(p, v, __ATOMIC_RELAXED, __HIP_MEMORY_SCOPE_AGENT);
}

// Histogram walk: largest bucket such that count of entries in buckets >= it
// reaches kneed. PLAIN-load version (prior-kernel data only).
__device__ __forceinline__ void walk_plain(const unsigned int* __restrict__ g,
                                           unsigned int kneed_in,
                                           unsigned int& bucket, unsigned int& kneed_out) {
    __shared__ unsigned int chunks[256];
    __shared__ unsigned int res[2];
    int t = threadIdx.x;
    unsigned int s = 0;
#pragma unroll
    for (int i = 0; i < 8; ++i) s += g[t * 8 + i];
    chunks[t] = s;
    __syncthreads();
    if (t == 0) {
        unsigned int cum = 0; int Cc_ = 0;
        for (int ch = 255; ch >= 0; --ch) {
            if (cum + chunks[ch] >= kneed_in) { Cc_ = ch; break; }
            cum += chunks[ch];
        }
        unsigned int bkt = 0, kn = 1;
        for (int i = 7; i >= 0; --i) {
            unsigned int h = g[Cc_ * 8 + i];
            if (cum + h >= kneed_in) { bkt = (unsigned int)(Cc_ * 8 + i); kn = kneed_in - cum; break; }
            cum += h;
        }
        res[0] = bkt; res[1] = kn;
    }
    __syncthreads();
    bucket = res[0]; kneed_out = res[1];
    __syncthreads();
}

// Atomic-load walk (same-kernel cross-block data), cs = bins/256.
__device__ __forceinline__ void walk_atomic(const unsigned int* __restrict__ g, int cs,
                                            unsigned int kneed_in,
                                            unsigned int& bucket, unsigned int& kneed_out) {
    __shared__ unsigned int chunks[256];
    __shared__ unsigned int res[2];
    int t = threadIdx.x;
    unsigned int s = 0;
    for (int i = 0; i < cs; ++i) s += aload(&g[t * cs + i]);
    chunks[t] = s;
    __syncthreads();
    if (t == 0) {
        unsigned int cum = 0; int Cc_ = 0;
        for (int ch = 255; ch >= 0; --ch) {
            if (cum + chunks[ch] >= kneed_in) { Cc_ = ch; break; }
            cum += chunks[ch];
        }
        unsigned int bkt = 0, kn = 1;
        for (int i = cs - 1; i >= 0; --i) {
            unsigned int h = aload(&g[Cc_ * cs + i]);
            if (cum + h >= kneed_in) { bkt = (unsigned int)(Cc_ * cs + i); kn = kneed_in - cum; break; }
            cum += h;
        }
        res[0] = bkt; res[1] = kn;
    }
    __syncthreads();
    bucket = res[0]; kneed_out = res[1];
    __syncthreads();
}

// ---------------------------------------------------------------------------
// K1: pairwise adjacencies with fused per-row stats. 64x64 tile (512 wgs).
__global__ __launch_bounds__(256) void k_pairwise(const float* __restrict__ x,
                                                  double* __restrict__ E,
                                                  double* __restrict__ Ch,
                                                  double* __restrict__ Cc) {
    int b  = blockIdx.z;
    int i0 = blockIdx.y * 64;
    int j0 = blockIdx.x * 64;
    __shared__ double xi[64][65];
    __shared__ double xj[64][65];
    __shared__ double mi[64], ri_[64], si[64];
    __shared__ double mj[64], rj_[64], sj[64];

    int t  = threadIdx.x;
    int r  = t >> 2;
    int cb = (t & 3) * 16;
    const float* xb = x + (size_t)b * N * C;
    {
        const float4* pi = (const float4*)(xb + (size_t)(i0 + r) * C + cb);
        const float4* pj = (const float4*)(xb + (size_t)(j0 + r) * C + cb);
#pragma unroll
        for (int m4 = 0; m4 < 4; ++m4) {
            float4 fi = pi[m4], fj = pj[m4];
            xi[r][cb + 4 * m4 + 0] = (double)fi.x; xi[r][cb + 4 * m4 + 1] = (double)fi.y;
            xi[r][cb + 4 * m4 + 2] = (double)fi.z; xi[r][cb + 4 * m4 + 3] = (double)fi.w;
            xj[r][cb + 4 * m4 + 0] = (double)fj.x; xj[r][cb + 4 * m4 + 1] = (double)fj.y;
            xj[r][cb + 4 * m4 + 2] = (double)fj.z; xj[r][cb + 4 * m4 + 3] = (double)fj.w;
        }
    }
    __syncthreads();

    if (t < 128) {
        int row = t & 63;
        const double (*xs)[65] = (t < 64) ? xi : xj;
        double sum = 0.0, rr = 0.0;
#pragma unroll 8
        for (int c = 0; c < 64; ++c) { double v = xs[row][c]; sum += v; rr = fma(v, v, rr); }
        double m = sum / 64.0;
        double q = 0.0;
#pragma unroll 8
        for (int c = 0; c < 64; ++c) { double w = xs[row][c] - m; q = fma(w, w, q); }
        double sv = 1.0 / sqrt(q);
        if (t < 64) { mi[row] = m; ri_[row] = rr; si[row] = sv; }
        else        { mj[row] = m; rj_[row] = rr; sj[row] = sv; }
    }
    __syncthreads();

    int ty = t >> 4, tx = t & 15;
    double adot[4][4] = {};
    double amax[4][4] = {};
#pragma unroll 8
    for (int c = 0; c < 64; ++c) {
        double ai[4], aj[4];
#pragma unroll
        for (int p = 0; p < 4; ++p) ai[p] = xi[ty + 16 * p][c];
#pragma unroll
        for (int q = 0; q < 4; ++q) aj[q] = xj[tx + 16 * q][c];
#pragma unroll
        for (int p = 0; p < 4; ++p)
#pragma unroll
            for (int q = 0; q < 4; ++q) {
                double d = ai[p] - aj[q];
                amax[p][q] = fmax(amax[p][q], fabs(d));
                adot[p][q] = fma(ai[p], aj[q], adot[p][q]);
            }
    }

#pragma unroll
    for (int p = 0; p < 4; ++p) {
        int li = ty + 16 * p;
        int ii = i0 + li;
        double rri = ri_[li], mmi = mi[li], ssi = si[li];
#pragma unroll
        for (int q = 0; q < 4; ++q) {
            int lj = tx + 16 * q;
            int jj = j0 + lj;
            double dot = adot[p][q];
            double d2  = rri + rj_[lj] - 2.0 * dot;
            double e   = (ii == jj) ? 0.0 : sqrt(fmax(d2, 0.0));
            double cc  = (dot - 64.0 * mmi * mj[lj]) * ssi * sj[lj];
            cc = fmin(1.0, fmax(-1.0, cc));
            size_t idx = (size_t)b * S + (size_t)ii * N + jj;
            E[idx]  = e;
            Ch[idx] = amax[p][q];
            Cc[idx] = cc;
        }
    }
}

// ---------------------------------------------------------------------------
// K2: C = scale * A * B^T (fp64, MFMA). 64x64 tile, LDS double-buffered.
__global__ __launch_bounds__(256) void k_gemm_nt(const double* __restrict__ A,
                                                 const double* __restrict__ Bm,
                                                 double* __restrict__ Cm,
                                                 double scale) {
    int b = blockIdx.z;
    const double* Ab = A  + (size_t)b * S;
    const double* Bb = Bm + (size_t)b * S;
    double*       Cb = Cm + (size_t)b * S;
    int i0 = blockIdx.y * 64, j0 = blockIdx.x * 64;

    __shared__ double At[2][64][33];
    __shared__ double Bt[2][64][33];

    int t    = threadIdx.x;
    int lane = t & 63;
    int w    = t >> 6;
    int wr   = (w >> 1) * 32;
    int wc   = (w & 1) * 32;
    int fm   = lane & 15;
    int fk   = lane >> 4;

    int sr = t >> 2, sc0 = (t & 3) * 8;

    d4 acc00 = {0.0, 0.0, 0.0, 0.0};
    d4 acc01 = acc00, acc10 = acc00, acc11 = acc00;

    const double* ap = Ab + (size_t)(i0 + sr) * N + sc0;
    const double* bp = Bb + (size_t)(j0 + sr) * N + sc0;

    double pa[8], pb[8];
#pragma unroll
    for (int m = 0; m < 8; ++m) { pa[m] = ap[m]; pb[m] = bp[m]; }
#pragma unroll
    for (int m = 0; m < 8; ++m) { At[0][sr][sc0 + m] = pa[m]; Bt[0][sr][sc0 + m] = pb[m]; }
    __syncthreads();

    int cur = 0;
    for (int k0 = 0; k0 < N; k0 += 32) {
        bool has_next = (k0 + 32 < N);
        if (has_next) {
            ap += 32; bp += 32;
#pragma unroll
            for (int m = 0; m < 8; ++m) { pa[m] = ap[m]; pb[m] = bp[m]; }
        }
#pragma unroll
        for (int kq = 0; kq < 8; ++kq) {
            int kk = kq * 4 + fk;
            double a0 = At[cur][wr + fm][kk];
            double a1 = At[cur][wr + 16 + fm][kk];
            double b0 = Bt[cur][wc + fm][kk];
            double b1 = Bt[cur][wc + 16 + fm][kk];
            acc00 = __builtin_amdgcn_mfma_f64_16x16x4f64(a0, b0, acc00, 0, 0, 0);
            acc01 = __builtin_amdgcn_mfma_f64_16x16x4f64(a0, b1, acc01, 0, 0, 0);
            acc10 = __builtin_amdgcn_mfma_f64_16x16x4f64(a1, b0, acc10, 0, 0, 0);
            acc11 = __builtin_amdgcn_mfma_f64_16x16x4f64(a1, b1, acc11, 0, 0, 0);
        }
        if (has_next) {
            int nxt = cur ^ 1;
#pragma unroll
            for (int m = 0; m < 8; ++m) { At[nxt][sr][sc0 + m] = pa[m]; Bt[nxt][sr][sc0 + m] = pb[m]; }
            __syncthreads();
            cur = nxt;
        }
    }
    int r0 = i0 + wr + 4 * fk;
    int c0 = j0 + wc + fm;
#pragma unroll
    for (int r = 0; r < 4; ++r) {
        Cb[(size_t)(r0 + r)      * N + c0]      = acc00[r] * scale;
        Cb[(size_t)(r0 + r)      * N + c0 + 16] = acc01[r] * scale;
        Cb[(size_t)(r0 + 16 + r) * N + c0]      = acc10[r] * scale;
        Cb[(size_t)(r0 + 16 + r) * N + c0 + 16] = acc11[r] * scale;
    }
}

// ---------------------------------------------------------------------------
// K4: W = A * B (fp64, MFMA) + key32 epilogue + fused hist0 (bins key>>21).
__global__ __launch_bounds__(256) void k_gemm_nn(const double* __restrict__ A,
                                                 const double* __restrict__ Bm,
                                                 double* __restrict__ Wm,
                                                 unsigned int* __restrict__ kq_out,
                                                 unsigned int* __restrict__ g0) {
    int b = blockIdx.z;
    const double* Ab = A  + (size_t)b * S;
    const double* Bb = Bm + (size_t)b * S;
    double*       Wb = Wm + (size_t)b * S;
    unsigned int* kb = kq_out + (size_t)b * S;
    int i0 = blockIdx.y * 64, j0 = blockIdx.x * 64;

    __shared__ double At[2][64][33];
    __shared__ double Bt[2][32][65];
    __shared__ unsigned int h0[2048];

    int t    = threadIdx.x;
    int lane = t & 63;
    int w    = t >> 6;
    int wr   = (w >> 1) * 32;
    int wc   = (w & 1) * 32;
    int fm   = lane & 15;
    int fk   = lane >> 4;

    int sr = t >> 2, sc0 = (t & 3) * 8;   // A staging: 64 rows x 32 k
    int br = t >> 3, bc = (t & 7) * 8;    // B staging: 32 k x 64 cols

    for (int i = t; i < 2048; i += 256) h0[i] = 0u;

    d4 acc00 = {0.0, 0.0, 0.0, 0.0};
    d4 acc01 = acc00, acc10 = acc00, acc11 = acc00;

    const double* ap = Ab + (size_t)(i0 + sr) * N + sc0;
    const double* bp = Bb + (size_t)br * N + j0 + bc;

    double pa[8], pb[8];
#pragma unroll
    for (int m = 0; m < 8; ++m) { pa[m] = ap[m]; pb[m] = bp[m]; }
#pragma unroll
    for (int m = 0; m < 8; ++m) { At[0][sr][sc0 + m] = pa[m]; Bt[0][br][bc + m] = pb[m]; }
    __syncthreads();

    int cur = 0;
    for (int k0 = 0; k0 < N; k0 += 32) {
        bool has_next = (k0 + 32 < N);
        if (has_next) {
            ap += 32; bp += (size_t)32 * N;
#pragma unroll
            for (int m = 0; m < 8; ++m) { pa[m] = ap[m]; pb[m] = bp[m]; }
        }
#pragma unroll
        for (int kq = 0; kq < 8; ++kq) {
            int kk = kq * 4 + fk;
            double a0 = At[cur][wr + fm][kk];
            double a1 = At[cur][wr + 16 + fm][kk];
            double b0 = Bt[cur][kk][wc + fm];
            double b1 = Bt[cur][kk][wc + 16 + fm];
            acc00 = __builtin_amdgcn_mfma_f64_16x16x4f64(a0, b0, acc00, 0, 0, 0);
            acc01 = __builtin_amdgcn_mfma_f64_16x16x4f64(a0, b1, acc01, 0, 0, 0);
            acc10 = __builtin_amdgcn_mfma_f64_16x16x4f64(a1, b0, acc10, 0, 0, 0);
            acc11 = __builtin_amdgcn_mfma_f64_16x16x4f64(a1, b1, acc11, 0, 0, 0);
        }
        if (has_next) {
            int nxt = cur ^ 1;
#pragma unroll
            for (int m = 0; m < 8; ++m) { At[nxt][sr][sc0 + m] = pa[m]; Bt[nxt][br][bc + m] = pb[m]; }
            __syncthreads();
            cur = nxt;
        }
    }
    int r0 = i0 + wr + 4 * fk;
    int c0 = j0 + wc + fm;
#pragma unroll
    for (int r = 0; r < 4; ++r) {
        double w00 = acc00[r], w01 = acc01[r], w10 = acc10[r], w11 = acc11[r];
        size_t i00 = (size_t)(r0 + r)      * N + c0;
        size_t i01 = (size_t)(r0 + r)      * N + c0 + 16;
        size_t i10 = (size_t)(r0 + 16 + r) * N + c0;
        size_t i11 = (size_t)(r0 + 16 + r) * N + c0 + 16;
        unsigned int k00 = (unsigned int)(d2key(w00) >> 32);
        unsigned int k01 = (unsigned int)(d2key(w01) >> 32);
        unsigned int k10 = (unsigned int)(d2key(w10) >> 32);
        unsigned int k11 = (unsigned int)(d2key(w11) >> 32);
        Wb[i00] = w00; kb[i00] = k00;
        Wb[i01] = w01; kb[i01] = k01;
        Wb[i10] = w10; kb[i10] = k10;
        Wb[i11] = w11; kb[i11] = k11;
        atomicAdd(&h0[k00 >> 21], 1u);
        atomicAdd(&h0[k01 >> 21], 1u);
        atomicAdd(&h0[k10 >> 21], 1u);
        atomicAdd(&h0[k11 >> 21], 1u);
    }
    __syncthreads();
    unsigned int* g = g0 + b * 2048;
    for (int i = t; i < 2048; i += 256)
        if (h0[i]) __hip_atomic_fetch_add(&g[i], h0[i], __ATOMIC_RELAXED,
                                          __HIP_MEMORY_SCOPE_AGENT);
}

// ---------------------------------------------------------------------------
// K3: fp64 row softmax. Wave per row, shuffle-only; 512 wgs.
__global__ __launch_bounds__(256) void k_softmax(double* __restrict__ L) {
    int row = (blockIdx.x << 2) + (threadIdx.x >> 6);
    int ln  = threadIdx.x & 63;
    double* p = L + (size_t)row * N;

    double v[16];
#pragma unroll
    for (int q = 0; q < 16; ++q) v[q] = p[ln + 64 * q];

    double mx = v[0];
#pragma unroll
    for (int q = 1; q < 16; ++q) mx = fmax(mx, v[q]);
#pragma unroll
    for (int off = 32; off >= 1; off >>= 1) mx = fmax(mx, __shfl_xor(mx, off));

    double s = 0.0;
#pragma unroll
    for (int q = 0; q < 16; ++q) { v[q] = exp(v[q] - mx); s += v[q]; }
#pragma unroll
    for (int off = 32; off >= 1; off >>= 1) s += __shfl_xor(s, off);

#pragma unroll
    for (int q = 0; q < 16; ++q) p[ln + 64 * q] = v[q] / s;
}

// ---------------------------------------------------------------------------
// K5 pass A: ONE device sweep, zero grid barriers.
// Walk g0 (prior-kernel data) -> B0. Write out=1 for keys above the B0
// bucket, 0 otherwise; compact B0-bucket elements into per-segment buffers
// (plain stores, owner-block-only; visible to pass B via kernel boundary).
__global__ __launch_bounds__(256) void k_passA(const unsigned int* __restrict__ key32,
                                               const unsigned int* __restrict__ g0,
                                               unsigned int* __restrict__ cand,   // [2][512][2048]
                                               unsigned int* __restrict__ segcnt, // [2][512]
                                               float* __restrict__ out) {
    int blk = blockIdx.x, t = threadIdx.x;
    int b = blk >> 7, lb = blk & 127;
    int lane = t & 63, wv = t >> 6;

    unsigned int B0, kn1;
    walk_plain(g0 + b * 2048, (unsigned int)KSEL, B0, kn1);
    (void)kn1;

    __shared__ unsigned int lc[4];
    if (t < 4) lc[t] = 0u;
    __syncthreads();

    const uint4* k4 = (const uint4*)(key32 + (size_t)b * S + (size_t)lb * 8192);
    float4* ob = (float4*)(out + (size_t)b * S + (size_t)lb * 8192);
    unsigned long long lmask = (1ULL << lane) - 1ULL;

#pragma unroll
    for (int it = 0; it < 8; ++it) {
        uint4 kv = k4[it * 256 + t];
        unsigned int ks[4] = {kv.x, kv.y, kv.z, kv.w};
        int segLocal = (it * 4 + wv) >> 3;   // wave-uniform (256-elem span in 2048 seg)
        float ov[4];
#pragma unroll
        for (int c = 0; c < 4; ++c) {
            unsigned int k = ks[c];
            unsigned int b0e = k >> 21;
            ov[c] = (b0e > B0) ? 1.0f : 0.0f;
            bool m = (b0e == B0);
            unsigned long long mb = __ballot(m);
            if (mb != 0ULL) {
                int ldr = __ffsll((long long)mb) - 1;
                unsigned int base = 0;
                if (lane == ldr) base = atomicAdd(&lc[segLocal], (unsigned int)__popcll(mb));
                base = __shfl(base, ldr, 64);
                if (m) {
                    unsigned int pos = base + (unsigned int)__popcll(mb & lmask);
                    int eloc = it * 1024 + t * 4 + c;           // 0..8191
                    unsigned int entry = ((k & 0x1FFFFFu) << 11) | (unsigned int)(eloc & 2047);
                    cand[((size_t)b * NSEG + lb * 4 + segLocal) * SEGSZ + pos] = entry;
                }
            }
        }
        ob[it * 256 + t] = make_float4(ov[0], ov[1], ov[2], ov[3]);
    }
    __syncthreads();
    if (t < 4) segcnt[b * NSEG + lb * 4 + t] = lc[t];
}

// ---------------------------------------------------------------------------
// K5 pass B: 64 blocks, small data only (~2-3 MB typical). Two hist levels
// over compacted entries, exact (low32(W),idx) tie-break, owner-segment
// fix-up (out lines clean at kernel start; one writer per line).
__device__ __forceinline__ void gridbar64(unsigned int* bar, unsigned int* phase) {
    asm volatile("s_waitcnt vmcnt(0)" ::: "memory");
    __syncthreads();
    if (threadIdx.x == 0) {
        unsigned int ph = ++(*phase);
        unsigned int a = __hip_atomic_fetch_add(&bar[0], 1u, __ATOMIC_RELAXED,
                                                __HIP_MEMORY_SCOPE_AGENT) + 1u;
        if (a == ph * (unsigned int)PBBLK) astore(&bar[16], ph);
        while (aload(&bar[16]) < ph) __builtin_amdgcn_s_sleep(4);
        asm volatile("" ::: "memory");
    }
    __syncthreads();
}

__global__ __launch_bounds__(256) void k_passB(const unsigned int* __restrict__ g0,
                                               const unsigned int* __restrict__ cand,
                                               const unsigned int* __restrict__ segcnt,
                                               const double* __restrict__ W,
                                               unsigned int* __restrict__ gh1,   // [2][2048]
                                               unsigned int* __restrict__ gh2,   // [2][1024]
                                               unsigned int* __restrict__ tiecnt,// [2*16]
                                               unsigned long long* __restrict__ tielist, // [2][S]
                                               unsigned long long* __restrict__ pub,     // [2*8]
                                               unsigned int* __restrict__ bar,
                                               float* __restrict__ out) {
    int blk = blockIdx.x, t = threadIdx.x;
    int b = blk >> 5, lbB = blk & 31;
    int lane = t & 63;
    unsigned int phase = 0;

    __shared__ unsigned int lh[2048];
    __shared__ unsigned long long s_p64;
    __shared__ unsigned int s_kk;

    unsigned int B0, kn1;
    walk_plain(g0 + b * 2048, (unsigned int)KSEL, B0, kn1);

    int seg0 = lbB * 16;                       // my 16 batch-local segments
    const unsigned int* cb  = cand + (size_t)b * NSEG * SEGSZ;
    const unsigned int* scb = segcnt + b * NSEG;
    const double* Wb = W + (size_t)b * S;

    // phase 1: hist entry bits 31:21 (= top 11 of low21)
    for (int i = t; i < 2048; i += 256) lh[i] = 0;
    __syncthreads();
    for (int sg = 0; sg < 16; ++sg) {
        unsigned int cnt = scb[seg0 + sg];
        const unsigned int* ce = cb + (size_t)(seg0 + sg) * SEGSZ;
        for (unsigned int e = t; e < cnt; e += 256) atomicAdd(&lh[ce[e] >> 21], 1u);
    }
    __syncthreads();
    for (int i = t; i < 2048; i += 256)
        if (lh[i]) __hip_atomic_fetch_add(&gh1[b * 2048 + i], lh[i], __ATOMIC_RELAXED,
                                          __HIP_MEMORY_SCOPE_AGENT);
    gridbar64(bar, &phase);

    // phase 2: walk gh1 -> B1; hist entry bits 20:11 among matches
    unsigned int B1, kn2;
    walk_atomic(gh1 + b * 2048, 8, kn1, B1, kn2);
    for (int i = t; i < 1024; i += 256) lh[i] = 0;
    __syncthreads();
    for (int sg = 0; sg < 16; ++sg) {
        unsigned int cnt = scb[seg0 + sg];
        const unsigned int* ce = cb + (size_t)(seg0 + sg) * SEGSZ;
        for (unsigned int e = t; e < cnt; e += 256) {
            unsigned int v = ce[e];
            if ((v >> 21) == B1) atomicAdd(&lh[(v >> 11) & 0x3FFu], 1u);
        }
    }
    __syncthreads();
    for (int i = t; i < 1024; i += 256)
        if (lh[i]) __hip_atomic_fetch_add(&gh2[b * 1024 + i], lh[i], __ATOMIC_RELAXED,
                                          __HIP_MEMORY_SCOPE_AGENT);
    gridbar64(bar, &phase);

    // phase 3: walk gh2 -> B2; T21 = full low-21 cutoff bucket; collect exact
    // full-key32 ties as packed (low32(Wkey)<<20 | idx)
    unsigned int B2, kn3;
    walk_atomic(gh2 + b * 1024, 4, kn2, B2, kn3);
    unsigned int T21 = (B1 << 10) | B2;
    unsigned long long lmask = (1ULL << lane) - 1ULL;
    for (int sg = 0; sg < 16; ++sg) {
        unsigned int cnt = scb[seg0 + sg];
        const unsigned int* ce = cb + (size_t)(seg0 + sg) * SEGSZ;
        for (unsigned int e0 = 0; e0 < cnt; e0 += 256) {
            unsigned int e = e0 + t;
            bool m = false;
            unsigned int v = 0;
            if (e < cnt) { v = ce[e]; m = ((v >> 11) == T21); }
            unsigned long long mb = __ballot(m);
            if (mb != 0ULL) {
                int ldr = __ffsll((long long)mb) - 1;
                unsigned int base = 0;
                if (lane == ldr)
                    base = __hip_atomic_fetch_add(&tiecnt[b * 16], (unsigned int)__popcll(mb),
                                                  __ATOMIC_RELAXED, __HIP_MEMORY_SCOPE_AGENT);
                base = __shfl(base, ldr, 64);
                if (m) {
                    unsigned int pos = base + (unsigned int)__popcll(mb & lmask);
                    unsigned int idx = (unsigned int)(seg0 + sg) * SEGSZ + (v & 2047u);
                    unsigned int low = (unsigned int)d2key(Wb[idx]);
                    unsigned long long pk = (((unsigned long long)low) << 20) |
                                            (unsigned long long)idx;
                    astore64(&tielist[(size_t)b * S + pos], pk);
                }
            }
        }
    }
    gridbar64(bar, &phase);

    // phase 4: leader per batch radix-selects 52-bit packed cutoff
    if (lbB == 0) {
        unsigned int c2 = aload(&tiecnt[b * 16]);
        const unsigned long long* tl = tielist + (size_t)b * S;
        unsigned long long rp = 0ULL;
        unsigned int rk = kn3;
#pragma unroll 1
        for (int pass = 0; pass < 7; ++pass) {
            int shift = 48 - 8 * pass;
            lh[t] = 0;
            __syncthreads();
            for (unsigned int e = t; e < c2; e += 256) {
                unsigned long long p = tl[e];   // plain: coherence-point-written
                if ((p >> (shift + 8)) == (rp >> (shift + 8)))
                    atomicAdd(&lh[(unsigned int)((p >> shift) & 255ULL)], 1u);
            }
            __syncthreads();
            if (t == 0) {
                unsigned int cum = 0; int bucket = 0;
                for (int i = 255; i >= 0; --i) {
                    unsigned int h = lh[i];
                    if (cum + h >= rk) { bucket = i; break; }
                    cum += h;
                }
                s_p64 = rp | (((unsigned long long)bucket) << shift);
                s_kk  = rk - cum;
            }
            __syncthreads();
            rp = s_p64; rk = s_kk;
            __syncthreads();
        }
        if (t == 0) astore64(&pub[b * 8], (1ULL << 63) | rp);
    }

    if (t == 0) {
        unsigned long long v;
        while (((v = aload64(&pub[b * 8])) >> 63) == 0ULL) __builtin_amdgcn_s_sleep(4);
        s_p64 = v;
    }
    __syncthreads();
    unsigned long long Cpk = s_p64 & 0x7FFFFFFFFFFFFFFFULL;

    // phase 5: fix-up my own segments (out clean at kernel start; one writer
    // per line by segment construction). Placeholder 0 covers the rest.
    float* outb = out + (size_t)b * S;
    for (int sg = 0; sg < 16; ++sg) {
        unsigned int cnt = scb[seg0 + sg];
        const unsigned int* ce = cb + (size_t)(seg0 + sg) * SEGSZ;
        for (unsigned int e = t; e < cnt; e += 256) {
            unsigned int v = ce[e];
            unsigned int t21v = v >> 11;
            unsigned int idx = (unsigned int)(seg0 + sg) * SEGSZ + (v & 2047u);
            if (t21v > T21) {
                outb[idx] = 1.0f;
            } else if (t21v == T21) {
                unsigned int low = (unsigned int)d2key(Wb[idx]);
                unsigned long long pk = (((unsigned long long)low) << 20) |
                                        (unsigned long long)idx;
                if (pk >= Cpk) outb[idx] = 1.0f;
            }
        }
    }
}

// ---------------------------------------------------------------------------
extern "C" void kernel_launch(void* const* d_in, const int* in_sizes, int n_in,
                              void* d_out, int out_size, void* d_ws, size_t ws_size,
                              hipStream_t stream) {
    const float* x = (const float*)d_in[0];
    float* out = (float*)d_out;

    char* ws = (char*)d_ws;
    size_t off = 0;
    auto alloc = [&](size_t bytes) -> void* {
        void* p = ws + off;
        off += (bytes + 255) & ~(size_t)255;
        return p;
    };

    double* E     = (double*)alloc((size_t)BB * S * sizeof(double));       // 16 MB
    double* Ch    = (double*)alloc((size_t)BB * S * sizeof(double));       // 16 MB
    double* Cc    = (double*)alloc((size_t)BB * S * sizeof(double));       // 16 MB
    double* L     = (double*)alloc((size_t)BB * S * sizeof(double));       // 16 MB
    unsigned int* key32 = (unsigned int*)alloc((size_t)BB * S * sizeof(unsigned int)); // 8 MB
    double* W     = E;   // E dead after gemm_nt -> W
    unsigned int* cand = (unsigned int*)L;          // L dead after gemm_nn (8 MB used)
    unsigned long long* tielist = (unsigned long long*)Ch;  // Ch dead after gemm_nt (16 MB)

    // zeroed scratch: g0[4096] gh1[4096] gh2[2048] tiecnt[32] bar[512] pub[16 u64]
    unsigned int* selz = (unsigned int*)alloc((4096 + 4096 + 2048 + 32 + 512 + 32) * sizeof(unsigned int));
    unsigned int* g0     = selz;
    unsigned int* gh1    = selz + 4096;
    unsigned int* gh2    = selz + 8192;
    unsigned int* tiecnt = selz + 10240;
    unsigned int* bar    = selz + 10272;
    unsigned long long* pub = (unsigned long long*)(selz + 10784);
    unsigned int* segcnt = (unsigned int*)alloc((size_t)BB * NSEG * sizeof(unsigned int)); // fully overwritten

    // 0) zero selection scratch
    hipMemsetAsync(selz, 0, (4096 + 4096 + 2048 + 32 + 512 + 32) * sizeof(unsigned int), stream);

    // 1) pairwise adjacencies (fused per-row stats)
    k_pairwise<<<dim3(N / 64, N / 64, BB), 256, 0, stream>>>(x, E, Ch, Cc);

    // 2) logits = (E @ Ch^T) * 1/8
    k_gemm_nt<<<dim3(N / 64, N / 64, BB), 256, 0, stream>>>(E, Ch, L, 0.125);

    // 3) softmax rows
    k_softmax<<<512, 256, 0, stream>>>(L);

    // 4) weighted = attn @ Cc + key32 epilogue + fused hist0
    k_gemm_nn<<<dim3(N / 64, N / 64, BB), 256, 0, stream>>>(L, Cc, W, key32, g0);

    // 5) pass A: single sweep — mask non-bucket, compact bucket (no barriers)
    k_passA<<<256, 256, 0, stream>>>(key32, g0, cand, segcnt, out);

    // 6) pass B: small-data refine + exact tie-break + owner-segment fix-up
    k_passB<<<PBBLK, 256, 0, stream>>>(g0, cand, segcnt, W, gh1, gh2, tiecnt,
                                       tielist, pub, bar, out);
}

// Round 16
// 403.581 us; speedup vs baseline: 1.1394x; 1.1394x over previous
//
#include <hip/hip_runtime.h>
#include <hip/hip_bf16.h>

// Problem constants (from setup_inputs: x = [2, 1024, 64] fp32)
constexpr int BB = 2;
constexpr int N  = 1024;
constexpr int C  = 64;
constexpr int S  = N * N;          // 1048576 = 2^20
constexpr int KSEL = S / 6;        // 174762 entries set to 1 per batch
constexpr int EQCAP = S;           // tie capacity per batch == batch size
constexpr int NSELBLK = 256;
constexpr int NZ = 4096 + 4096 + 32 + 512 + 128;   // select scratch u32 count

typedef double d4 __attribute__((ext_vector_type(4)));

// Order-preserving uint64 mapping of fp64 (monotone: a<b <=> key(a)<key(b))
__device__ __forceinline__ unsigned long long d2key(double d) {
    unsigned long long u = (unsigned long long)__double_as_longlong(d);
    return (u & 0x8000000000000000ULL) ? ~u : (u | 0x8000000000000000ULL);
}

__device__ __forceinline__ unsigned int aload(const unsigned int* p) {
    return __hip_atomic_load(p, __ATOMIC_RELAXED, __HIP_MEMORY_SCOPE_AGENT);
}
__device__ __forceinline__ void astore(unsigned int* p, unsigned int v) {
    (void)__hip_atomic_exchange(p, v, __ATOMIC_RELAXED, __HIP_MEMORY_SCOPE_AGENT);
}
__device__ __forceinline__ unsigned long long aload64(const unsigned long long* p) {
    return __hip_atomic_load(p, __ATOMIC_RELAXED, __HIP_MEMORY_SCOPE_AGENT);
}
__device__ __forceinline__ void astore64(unsigned long long* p, unsigned long long v) {
    (void)__hip_atomic_exchange(p, v, __ATOMIC_RELAXED, __HIP_MEMORY_SCOPE_AGENT);
}

// Histogram walk (2048 bins): largest bucket such that count of entries in
// buckets >= it reaches kneed. PLAIN-load version (prior-kernel data only).
__device__ __forceinline__ void walk_plain(const unsigned int* __restrict__ g,
                                           unsigned int kneed_in,
                                           unsigned int& bucket, unsigned int& kneed_out) {
    __shared__ unsigned int chunks[256];
    __shared__ unsigned int res[2];
    int t = threadIdx.x;
    unsigned int s = 0;
#pragma unroll
    for (int i = 0; i < 8; ++i) s += g[t * 8 + i];
    chunks[t] = s;
    __syncthreads();
    if (t == 0) {
        unsigned int cum = 0; int Cc_ = 0;
        for (int ch = 255; ch >= 0; --ch) {
            if (cum + chunks[ch] >= kneed_in) { Cc_ = ch; break; }
            cum += chunks[ch];
        }
        unsigned int bkt = 0, kn = 1;
        for (int i = 7; i >= 0; --i) {
            unsigned int h = g[Cc_ * 8 + i];
            if (cum + h >= kneed_in) { bkt = (unsigned int)(Cc_ * 8 + i); kn = kneed_in - cum; break; }
            cum += h;
        }
        res[0] = bkt; res[1] = kn;
    }
    __syncthreads();
    bucket = res[0]; kneed_out = res[1];
    __syncthreads();
}

// Atomic-load version (same-kernel cross-block data); leader blocks only.
__device__ __forceinline__ void walk_atomic(const unsigned int* __restrict__ g,
                                            unsigned int kneed_in,
                                            unsigned int& bucket, unsigned int& kneed_out) {
    __shared__ unsigned int chunks[256];
    __shared__ unsigned int res[2];
    int t = threadIdx.x;
    unsigned int s = 0;
#pragma unroll
    for (int i = 0; i < 8; ++i) s += aload(&g[t * 8 + i]);
    chunks[t] = s;
    __syncthreads();
    if (t == 0) {
        unsigned int cum = 0; int Cc_ = 0;
        for (int ch = 255; ch >= 0; --ch) {
            if (cum + chunks[ch] >= kneed_in) { Cc_ = ch; break; }
            cum += chunks[ch];
        }
        unsigned int bkt = 0, kn = 1;
        for (int i = 7; i >= 0; --i) {
            unsigned int h = aload(&g[Cc_ * 8 + i]);
            if (cum + h >= kneed_in) { bkt = (unsigned int)(Cc_ * 8 + i); kn = kneed_in - cum; break; }
            cum += h;
        }
        res[0] = bkt; res[1] = kn;
    }
    __syncthreads();
    bucket = res[0]; kneed_out = res[1];
    __syncthreads();
}

// ---------------------------------------------------------------------------
// K1: pairwise adjacencies, TRIANGULAR grid (E/Ch/Cc all symmetric — i<->j
// commutes bitwise: a+b, a*b, fma, fabs are commutative-exact). Off-diagonal
// tiles write direct + LDS-transposed mirror. Block (0,0,0) also zeroes the
// selection scratch (read 2+ kernel boundaries later).
__global__ __launch_bounds__(256) void k_pairwise(const float* __restrict__ x,
                                                  double* __restrict__ E,
                                                  double* __restrict__ Ch,
                                                  double* __restrict__ Cc,
                                                  unsigned int* __restrict__ selz) {
    int b  = blockIdx.z;
    int by = blockIdx.y, bx = blockIdx.x;
    int t  = threadIdx.x;

    if (b == 0 && bx == 0 && by == 0)
        for (int i = t; i < NZ; i += 256) selz[i] = 0u;

    if (by > bx) return;                 // triangular: i0 <= j0
    int i0 = by * 64, j0 = bx * 64;

    __shared__ double xi[64][65];
    __shared__ double xj[64][65];
    __shared__ double mi[64], ri_[64], si[64];
    __shared__ double mj[64], rj_[64], sj[64];

    int r  = t >> 2;
    int cb = (t & 3) * 16;
    const float* xb = x + (size_t)b * N * C;
    {
        const float4* pi = (const float4*)(xb + (size_t)(i0 + r) * C + cb);
        const float4* pj = (const float4*)(xb + (size_t)(j0 + r) * C + cb);
#pragma unroll
        for (int m4 = 0; m4 < 4; ++m4) {
            float4 fi = pi[m4], fj = pj[m4];
            xi[r][cb + 4 * m4 + 0] = (double)fi.x; xi[r][cb + 4 * m4 + 1] = (double)fi.y;
            xi[r][cb + 4 * m4 + 2] = (double)fi.z; xi[r][cb + 4 * m4 + 3] = (double)fi.w;
            xj[r][cb + 4 * m4 + 0] = (double)fj.x; xj[r][cb + 4 * m4 + 1] = (double)fj.y;
            xj[r][cb + 4 * m4 + 2] = (double)fj.z; xj[r][cb + 4 * m4 + 3] = (double)fj.w;
        }
    }
    __syncthreads();

    if (t < 128) {
        int row = t & 63;
        const double (*xs)[65] = (t < 64) ? xi : xj;
        double sum = 0.0, rr = 0.0;
#pragma unroll 8
        for (int c = 0; c < 64; ++c) { double v = xs[row][c]; sum += v; rr = fma(v, v, rr); }
        double m = sum / 64.0;
        double q = 0.0;
#pragma unroll 8
        for (int c = 0; c < 64; ++c) { double w = xs[row][c] - m; q = fma(w, w, q); }
        double sv = 1.0 / sqrt(q);
        if (t < 64) { mi[row] = m; ri_[row] = rr; si[row] = sv; }
        else        { mj[row] = m; rj_[row] = rr; sj[row] = sv; }
    }
    __syncthreads();

    int ty = t >> 4, tx = t & 15;
    double adot[4][4] = {};
    double amax[4][4] = {};
#pragma unroll 8
    for (int c = 0; c < 64; ++c) {
        double ai[4], aj[4];
#pragma unroll
        for (int p = 0; p < 4; ++p) ai[p] = xi[ty + 16 * p][c];
#pragma unroll
        for (int q = 0; q < 4; ++q) aj[q] = xj[tx + 16 * q][c];
#pragma unroll
        for (int p = 0; p < 4; ++p)
#pragma unroll
            for (int q = 0; q < 4; ++q) {
                double d = ai[p] - aj[q];
                amax[p][q] = fmax(amax[p][q], fabs(d));
                adot[p][q] = fma(ai[p], aj[q], adot[p][q]);
            }
    }

    double ev[4][4], cv[4][4];
#pragma unroll
    for (int p = 0; p < 4; ++p) {
        int li = ty + 16 * p;
        int ii = i0 + li;
        double rri = ri_[li], mmi = mi[li], ssi = si[li];
#pragma unroll
        for (int q = 0; q < 4; ++q) {
            int lj = tx + 16 * q;
            int jj = j0 + lj;
            double dot = adot[p][q];
            double d2  = rri + rj_[lj] - 2.0 * dot;
            double e   = (ii == jj) ? 0.0 : sqrt(fmax(d2, 0.0));
            double cc  = (dot - 64.0 * mmi * mj[lj]) * ssi * sj[lj];
            cc = fmin(1.0, fmax(-1.0, cc));
            ev[p][q] = e; cv[p][q] = cc;
            size_t idx = (size_t)b * S + (size_t)ii * N + jj;
            E[idx]  = e;
            Ch[idx] = amax[p][q];
            Cc[idx] = cc;
        }
    }

    if (i0 != j0) {
        // mirrored (transposed) writes via LDS staging (coalesced)
        double* mats[3] = {E, Ch, Cc};
        int rr2 = t >> 2, cb2 = (t & 3) * 16;
#pragma unroll
        for (int mm = 0; mm < 3; ++mm) {
            __syncthreads();
#pragma unroll
            for (int p = 0; p < 4; ++p)
#pragma unroll
                for (int q = 0; q < 4; ++q) {
                    double v = (mm == 0) ? ev[p][q] : (mm == 1) ? amax[p][q] : cv[p][q];
                    xi[tx + 16 * q][ty + 16 * p] = v;   // [lj][li]
                }
            __syncthreads();
            double* row = mats[mm] + (size_t)b * S + (size_t)(j0 + rr2) * N + i0 + cb2;
#pragma unroll
            for (int m = 0; m < 16; ++m) row[m] = xi[rr2][cb2 + m];
        }
    }
}

// ---------------------------------------------------------------------------
// K2: C = scale * A * B^T (fp64, MFMA). 64x64 tile, LDS double-buffered.
__global__ __launch_bounds__(256) void k_gemm_nt(const double* __restrict__ A,
                                                 const double* __restrict__ Bm,
                                                 double* __restrict__ Cm,
                                                 double scale) {
    int b = blockIdx.z;
    const double* Ab = A  + (size_t)b * S;
    const double* Bb = Bm + (size_t)b * S;
    double*       Cb = Cm + (size_t)b * S;
    int i0 = blockIdx.y * 64, j0 = blockIdx.x * 64;

    __shared__ double At[2][64][33];
    __shared__ double Bt[2][64][33];

    int t    = threadIdx.x;
    int lane = t & 63;
    int w    = t >> 6;
    int wr   = (w >> 1) * 32;
    int wc   = (w & 1) * 32;
    int fm   = lane & 15;
    int fk   = lane >> 4;

    int sr = t >> 2, sc0 = (t & 3) * 8;

    d4 acc00 = {0.0, 0.0, 0.0, 0.0};
    d4 acc01 = acc00, acc10 = acc00, acc11 = acc00;

    const double* ap = Ab + (size_t)(i0 + sr) * N + sc0;
    const double* bp = Bb + (size_t)(j0 + sr) * N + sc0;

    double pa[8], pb[8];
#pragma unroll
    for (int m = 0; m < 8; ++m) { pa[m] = ap[m]; pb[m] = bp[m]; }
#pragma unroll
    for (int m = 0; m < 8; ++m) { At[0][sr][sc0 + m] = pa[m]; Bt[0][sr][sc0 + m] = pb[m]; }
    __syncthreads();

    int cur = 0;
    for (int k0 = 0; k0 < N; k0 += 32) {
        bool has_next = (k0 + 32 < N);
        if (has_next) {
            ap += 32; bp += 32;
#pragma unroll
            for (int m = 0; m < 8; ++m) { pa[m] = ap[m]; pb[m] = bp[m]; }
        }
#pragma unroll
        for (int kq = 0; kq < 8; ++kq) {
            int kk = kq * 4 + fk;
            double a0 = At[cur][wr + fm][kk];
            double a1 = At[cur][wr + 16 + fm][kk];
            double b0 = Bt[cur][wc + fm][kk];
            double b1 = Bt[cur][wc + 16 + fm][kk];
            acc00 = __builtin_amdgcn_mfma_f64_16x16x4f64(a0, b0, acc00, 0, 0, 0);
            acc01 = __builtin_amdgcn_mfma_f64_16x16x4f64(a0, b1, acc01, 0, 0, 0);
            acc10 = __builtin_amdgcn_mfma_f64_16x16x4f64(a1, b0, acc10, 0, 0, 0);
            acc11 = __builtin_amdgcn_mfma_f64_16x16x4f64(a1, b1, acc11, 0, 0, 0);
        }
        if (has_next) {
            int nxt = cur ^ 1;
#pragma unroll
            for (int m = 0; m < 8; ++m) { At[nxt][sr][sc0 + m] = pa[m]; Bt[nxt][sr][sc0 + m] = pb[m]; }
            __syncthreads();
            cur = nxt;
        }
    }
    int r0 = i0 + wr + 4 * fk;
    int c0 = j0 + wc + fm;
#pragma unroll
    for (int r = 0; r < 4; ++r) {
        Cb[(size_t)(r0 + r)      * N + c0]      = acc00[r] * scale;
        Cb[(size_t)(r0 + r)      * N + c0 + 16] = acc01[r] * scale;
        Cb[(size_t)(r0 + 16 + r) * N + c0]      = acc10[r] * scale;
        Cb[(size_t)(r0 + 16 + r) * N + c0 + 16] = acc11[r] * scale;
    }
}

// ---------------------------------------------------------------------------
// K4: W = A * B (fp64, MFMA) + key32 epilogue + fused hist0 (bins key>>21).
__global__ __launch_bounds__(256) void k_gemm_nn(const double* __restrict__ A,
                                                 const double* __restrict__ Bm,
                                                 double* __restrict__ Wm,
                                                 unsigned int* __restrict__ kq_out,
                                                 unsigned int* __restrict__ g0) {
    int b = blockIdx.z;
    const double* Ab = A  + (size_t)b * S;
    const double* Bb = Bm + (size_t)b * S;
    double*       Wb = Wm + (size_t)b * S;
    unsigned int* kb = kq_out + (size_t)b * S;
    int i0 = blockIdx.y * 64, j0 = blockIdx.x * 64;

    __shared__ double At[2][64][33];
    __shared__ double Bt[2][32][65];
    __shared__ unsigned int h0[2048];

    int t    = threadIdx.x;
    int lane = t & 63;
    int w    = t >> 6;
    int wr   = (w >> 1) * 32;
    int wc   = (w & 1) * 32;
    int fm   = lane & 15;
    int fk   = lane >> 4;

    int sr = t >> 2, sc0 = (t & 3) * 8;   // A staging: 64 rows x 32 k
    int br = t >> 3, bc = (t & 7) * 8;    // B staging: 32 k x 64 cols

    for (int i = t; i < 2048; i += 256) h0[i] = 0u;

    d4 acc00 = {0.0, 0.0, 0.0, 0.0};
    d4 acc01 = acc00, acc10 = acc00, acc11 = acc00;

    const double* ap = Ab + (size_t)(i0 + sr) * N + sc0;
    const double* bp = Bb + (size_t)br * N + j0 + bc;

    double pa[8], pb[8];
#pragma unroll
    for (int m = 0; m < 8; ++m) { pa[m] = ap[m]; pb[m] = bp[m]; }
#pragma unroll
    for (int m = 0; m < 8; ++m) { At[0][sr][sc0 + m] = pa[m]; Bt[0][br][bc + m] = pb[m]; }
    __syncthreads();

    int cur = 0;
    for (int k0 = 0; k0 < N; k0 += 32) {
        bool has_next = (k0 + 32 < N);
        if (has_next) {
            ap += 32; bp += (size_t)32 * N;
#pragma unroll
            for (int m = 0; m < 8; ++m) { pa[m] = ap[m]; pb[m] = bp[m]; }
        }
#pragma unroll
        for (int kq = 0; kq < 8; ++kq) {
            int kk = kq * 4 + fk;
            double a0 = At[cur][wr + fm][kk];
            double a1 = At[cur][wr + 16 + fm][kk];
            double b0 = Bt[cur][kk][wc + fm];
            double b1 = Bt[cur][kk][wc + 16 + fm];
            acc00 = __builtin_amdgcn_mfma_f64_16x16x4f64(a0, b0, acc00, 0, 0, 0);
            acc01 = __builtin_amdgcn_mfma_f64_16x16x4f64(a0, b1, acc01, 0, 0, 0);
            acc10 = __builtin_amdgcn_mfma_f64_16x16x4f64(a1, b0, acc10, 0, 0, 0);
            acc11 = __builtin_amdgcn_mfma_f64_16x16x4f64(a1, b1, acc11, 0, 0, 0);
        }
        if (has_next) {
            int nxt = cur ^ 1;
#pragma unroll
            for (int m = 0; m < 8; ++m) { At[nxt][sr][sc0 + m] = pa[m]; Bt[nxt][br][bc + m] = pb[m]; }
            __syncthreads();
            cur = nxt;
        }
    }
    int r0 = i0 + wr + 4 * fk;
    int c0 = j0 + wc + fm;
#pragma unroll
    for (int r = 0; r < 4; ++r) {
        double w00 = acc00[r], w01 = acc01[r], w10 = acc10[r], w11 = acc11[r];
        size_t i00 = (size_t)(r0 + r)      * N + c0;
        size_t i01 = (size_t)(r0 + r)      * N + c0 + 16;
        size_t i10 = (size_t)(r0 + 16 + r) * N + c0;
        size_t i11 = (size_t)(r0 + 16 + r) * N + c0 + 16;
        unsigned int k00 = (unsigned int)(d2key(w00) >> 32);
        unsigned int k01 = (unsigned int)(d2key(w01) >> 32);
        unsigned int k10 = (unsigned int)(d2key(w10) >> 32);
        unsigned int k11 = (unsigned int)(d2key(w11) >> 32);
        Wb[i00] = w00; kb[i00] = k00;
        Wb[i01] = w01; kb[i01] = k01;
        Wb[i10] = w10; kb[i10] = k10;
        Wb[i11] = w11; kb[i11] = k11;
        atomicAdd(&h0[k00 >> 21], 1u);
        atomicAdd(&h0[k01 >> 21], 1u);
        atomicAdd(&h0[k10 >> 21], 1u);
        atomicAdd(&h0[k11 >> 21], 1u);
    }
    __syncthreads();
    unsigned int* g = g0 + b * 2048;
    for (int i = t; i < 2048; i += 256)
        if (h0[i]) __hip_atomic_fetch_add(&g[i], h0[i], __ATOMIC_RELAXED,
                                          __HIP_MEMORY_SCOPE_AGENT);
}

// ---------------------------------------------------------------------------
// K3: fp64 row softmax. Wave per row, shuffle-only; 512 wgs.
__global__ __launch_bounds__(256) void k_softmax(double* __restrict__ L) {
    int row = (blockIdx.x << 2) + (threadIdx.x >> 6);
    int ln  = threadIdx.x & 63;
    double* p = L + (size_t)row * N;

    double v[16];
#pragma unroll
    for (int q = 0; q < 16; ++q) v[q] = p[ln + 64 * q];

    double mx = v[0];
#pragma unroll
    for (int q = 1; q < 16; ++q) mx = fmax(mx, v[q]);
#pragma unroll
    for (int off = 32; off >= 1; off >>= 1) mx = fmax(mx, __shfl_xor(mx, off));

    double s = 0.0;
#pragma unroll
    for (int q = 0; q < 16; ++q) { v[q] = exp(v[q] - mx); s += v[q]; }
#pragma unroll
    for (int off = 32; off >= 1; off >>= 1) s += __shfl_xor(s, off);

#pragma unroll
    for (int q = 0; q < 16; ++q) p[ln + 64 * q] = v[q] / s;
}

// ---------------------------------------------------------------------------
// K5: fused selection (R14, proven 128 µs): 2 full passes + 2 grid barriers,
// leader-only atomic walks, owner-thread tie fixup.
__device__ __forceinline__ void gridbar(unsigned int* bar, unsigned int* phase) {
    asm volatile("s_waitcnt vmcnt(0)" ::: "memory");
    __syncthreads();
    if (threadIdx.x == 0) {
        unsigned int ph = ++(*phase);
        int g = (int)(blockIdx.x >> 4);
        unsigned int a1 = __hip_atomic_fetch_add(&bar[32 + g * 16], 1u,
                              __ATOMIC_RELAXED, __HIP_MEMORY_SCOPE_AGENT) + 1u;
        if (a1 == ph * 16u) {
            unsigned int a2 = __hip_atomic_fetch_add(&bar[0], 1u,
                                  __ATOMIC_RELAXED, __HIP_MEMORY_SCOPE_AGENT) + 1u;
            if (a2 == ph * 16u) astore(&bar[16], ph);
        }
        while (aload(&bar[16]) < ph) __builtin_amdgcn_s_sleep(4);
        asm volatile("" ::: "memory");
    }
    __syncthreads();
}

__global__ __launch_bounds__(256) void k_select(const unsigned int* __restrict__ key32,
                                                const double* __restrict__ W,
                                                const unsigned int* __restrict__ g0,
                                                unsigned int* __restrict__ g1,
                                                unsigned int* __restrict__ cnt,
                                                unsigned long long* __restrict__ cand,
                                                unsigned long long* __restrict__ pub,
                                                unsigned int* __restrict__ bar,
                                                float* __restrict__ out) {
    int blk = blockIdx.x, t = threadIdx.x;
    int b = blk >> 7, lb = blk & 127;
    int lane = t & 63;
    unsigned int phase = 0;

    __shared__ unsigned int lh[2048];
    __shared__ unsigned long long s_p64;
    __shared__ unsigned int s_kk;

    const uint4* k4 = (const uint4*)(key32 + (size_t)b * S + (size_t)lb * 8192);

    // ---- phase 1: walk g0 (plain — prior-kernel data), hist mid-11 bits ----
    unsigned int B0, kn1;
    walk_plain(g0 + b * 2048, (unsigned int)KSEL, B0, kn1);
    for (int i = t; i < 2048; i += 256) lh[i] = 0;
    __syncthreads();
#pragma unroll
    for (int it = 0; it < 8; ++it) {
        uint4 kv = k4[it * 256 + t];
        unsigned int ks[4] = {kv.x, kv.y, kv.z, kv.w};
#pragma unroll
        for (int c = 0; c < 4; ++c)
            if ((ks[c] >> 21) == B0) atomicAdd(&lh[(ks[c] >> 10) & 0x7FFu], 1u);
    }
    __syncthreads();
    for (int i = t; i < 2048; i += 256)
        if (lh[i]) __hip_atomic_fetch_add(&g1[b * 2048 + i], lh[i], __ATOMIC_RELAXED,
                                          __HIP_MEMORY_SCOPE_AGENT);
    gridbar(bar, &phase);

    // ---- phase 2a: LEADER-only walk of g1 (atomic), publish B1/kn2 ----
    if (lb == 0) {
        unsigned int B1l, kn2l;
        walk_atomic(g1 + b * 2048, kn1, B1l, kn2l);
        if (t == 0) {
            unsigned long long v = (1ULL << 63) |
                                   (((unsigned long long)B1l) << 32) |
                                   (unsigned long long)kn2l;
            astore64(&pub[b * 16], v);
            s_p64 = v;
        }
        __syncthreads();
    } else {
        if (t == 0) {
            unsigned long long v;
            while (((v = aload64(&pub[b * 16])) >> 63) == 0ULL)
                __builtin_amdgcn_s_sleep(4);
            s_p64 = v;
        }
        __syncthreads();
    }
    unsigned int B1  = (unsigned int)((s_p64 >> 32) & 0x7FFULL);
    unsigned int kn2 = (unsigned int)(s_p64 & 0xFFFFFFFFULL);
    __syncthreads();
    unsigned int pref22 = (B0 << 11) | B1;

    // ---- phase 2b: mask non-ties + tie collection ----
    unsigned long long lmask = (1ULL << lane) - 1ULL;
    unsigned long long* cb = cand + (size_t)b * EQCAP;
    const double* Wb = W + (size_t)b * S;
    float4* ob = (float4*)(out + (size_t)b * S + (size_t)lb * 8192);
#pragma unroll
    for (int it = 0; it < 8; ++it) {
        uint4 kv = k4[it * 256 + t];
        unsigned int ks[4] = {kv.x, kv.y, kv.z, kv.w};
        float ov[4];
#pragma unroll
        for (int c = 0; c < 4; ++c) {
            unsigned int k = ks[c];
            unsigned int t22 = k >> 10;
            bool m = (t22 == pref22);
            unsigned long long mb = __ballot(m);
            ov[c] = (t22 > pref22) ? 1.0f : 0.0f;   // ties: placeholder, fixed in 3b
            if (mb != 0ULL) {
                int ldr = __ffsll((long long)mb) - 1;
                unsigned int base = 0;
                if (lane == ldr)
                    base = __hip_atomic_fetch_add(&cnt[b * 16], (unsigned int)__popcll(mb),
                                                  __ATOMIC_RELAXED, __HIP_MEMORY_SCOPE_AGENT);
                base = __shfl(base, ldr, 64);
                if (m) {
                    unsigned int pos = base + (unsigned int)__popcll(mb & lmask);
                    if (pos < (unsigned int)EQCAP) {
                        int s = lb * 8192 + it * 1024 + t * 4 + c;
                        unsigned long long full = d2key(Wb[s]);
                        unsigned long long packed =
                            (((unsigned long long)(k & 0x3FFu)) << 52) |
                            ((full & 0xFFFFFFFFULL) << 20) |
                            (unsigned long long)(unsigned int)s;
                        astore64(&cb[pos], packed);
                    }
                }
            }
        }
        ob[it * 256 + t] = make_float4(ov[0], ov[1], ov[2], ov[3]);
    }
    gridbar(bar, &phase);

    // ---- phase 3a: leader radix-selects the packed cutoff (plain cand
    //      loads — coherence-point-written, no cached copies anywhere) ----
    if (lb == 0) {
        unsigned int c_ = aload(&cnt[b * 16]);
        if (c_ > (unsigned int)EQCAP) c_ = EQCAP;
        unsigned long long rpref = 0ULL;
        unsigned int rk = kn2;
#pragma unroll 1
        for (int pass = 0; pass < 8; ++pass) {
            int shift = 56 - 8 * pass;
            lh[t] = 0;
            __syncthreads();
            for (unsigned int e = t; e < c_; e += 256) {
                unsigned long long p = cb[e];
                bool match = (pass == 0) || ((p >> (shift + 8)) == (rpref >> (shift + 8)));
                if (match) atomicAdd(&lh[(unsigned int)((p >> shift) & 255ULL)], 1u);
            }
            __syncthreads();
            if (t == 0) {
                unsigned int cum = 0; int bucket = 0;
                for (int i = 255; i >= 0; --i) {
                    unsigned int h = lh[i];
                    if (cum + h >= rk) { bucket = i; break; }
                    cum += h;
                }
                s_p64 = rpref | (((unsigned long long)bucket) << shift);
                s_kk  = rk - cum;
            }
            __syncthreads();
            rpref = s_p64; rk = s_kk;
            __syncthreads();
        }
        if (t == 0) astore64(&pub[b * 16 + 8], (1ULL << 63) | rpref);
    }

    // ---- phase 3b: every block fixes up its OWN tile's ties ----
    if (t == 0) {
        unsigned long long v;
        while (((v = aload64(&pub[b * 16 + 8])) >> 63) == 0ULL)
            __builtin_amdgcn_s_sleep(4);
        s_p64 = v;
    }
    __syncthreads();
    unsigned long long Ccut = s_p64 & 0x7FFFFFFFFFFFFFFFULL;

    float* outb = out + (size_t)b * S;
#pragma unroll
    for (int it = 0; it < 8; ++it) {
        uint4 kv = k4[it * 256 + t];
        unsigned int ks[4] = {kv.x, kv.y, kv.z, kv.w};
#pragma unroll
        for (int c = 0; c < 4; ++c) {
            unsigned int k = ks[c];
            if ((k >> 10) == pref22) {
                int s = lb * 8192 + it * 1024 + t * 4 + c;
                unsigned long long full = d2key(Wb[s]);
                unsigned long long packed =
                    (((unsigned long long)(k & 0x3FFu)) << 52) |
                    ((full & 0xFFFFFFFFULL) << 20) |
                    (unsigned long long)(unsigned int)s;
                outb[s] = (packed >= Ccut) ? 1.0f : 0.0f;   // same thread wrote
            }                                               // the placeholder
        }
    }
}

// ---------------------------------------------------------------------------
extern "C" void kernel_launch(void* const* d_in, const int* in_sizes, int n_in,
                              void* d_out, int out_size, void* d_ws, size_t ws_size,
                              hipStream_t stream) {
    const float* x = (const float*)d_in[0];
    float* out = (float*)d_out;

    char* ws = (char*)d_ws;
    size_t off = 0;
    auto alloc = [&](size_t bytes) -> void* {
        void* p = ws + off;
        off += (bytes + 255) & ~(size_t)255;
        return p;
    };

    double* E     = (double*)alloc((size_t)BB * S * sizeof(double));       // 16 MB
    double* Ch    = (double*)alloc((size_t)BB * S * sizeof(double));       // 16 MB
    double* Cc    = (double*)alloc((size_t)BB * S * sizeof(double));       // 16 MB
    double* L     = (double*)alloc((size_t)BB * S * sizeof(double));       // 16 MB
    unsigned int* key32 = (unsigned int*)alloc((size_t)BB * S * sizeof(unsigned int)); // 8 MB
    double* W     = E;  // E dead after gemm_nt -> reuse for weighted

    // selection scratch (zeroed by k_pairwise block (0,0,0))
    // layout (u32): g0[4096] g1[4096] cnt[32] bar[512] pub[128]
    unsigned int* selz = (unsigned int*)alloc(NZ * sizeof(unsigned int));
    unsigned int* g0   = selz;
    unsigned int* g1   = selz + 4096;
    unsigned int* cnt  = selz + 8192;
    unsigned int* bar  = selz + 8224;
    unsigned long long* pub = (unsigned long long*)(selz + 8736);   // [2][16] u64
    unsigned long long* cand =
        (unsigned long long*)alloc((size_t)BB * EQCAP * sizeof(unsigned long long)); // 16 MB

    // 1) pairwise adjacencies (triangular grid; zeroes select scratch)
    k_pairwise<<<dim3(N / 64, N / 64, BB), 256, 0, stream>>>(x, E, Ch, Cc, selz);

    // 2) logits = (E @ Ch^T) * 1/8
    k_gemm_nt<<<dim3(N / 64, N / 64, BB), 256, 0, stream>>>(E, Ch, L, 0.125);

    // 3) softmax rows
    k_softmax<<<512, 256, 0, stream>>>(L);

    // 4) weighted = attn @ Cc + key32 epilogue + fused hist0
    k_gemm_nn<<<dim3(N / 64, N / 64, BB), 256, 0, stream>>>(L, Cc, W, key32, g0);

    // 5) fused selection (2 full passes, leader-only atomic walks)
    k_select<<<NSELBLK, 256, 0, stream>>>(key32, W, g0, g1, cnt, cand, pub, bar, out);
}